// Round 1
// baseline (559.534 us; speedup 1.0000x reference)
//
#include <hip/hip_runtime.h>
#include <hip/hip_bf16.h>

#define N_NODES 30000
#define HDIM 128     // H*D
#define DDIM 32
#define GGRP 128
#define TOUT 10
#define NEG_SLOPE 0.2f

// ---------------------------------------------------------------------------
// init: zero degree array, set pool accumulator to -inf
// ---------------------------------------------------------------------------
__global__ void init_kernel(int* __restrict__ deg, float* __restrict__ gpool,
                            int n, int gsize) {
    int i = blockIdx.x * blockDim.x + threadIdx.x;
    if (i < n) deg[i] = 0;
    if (i < gsize) gpool[i] = -__builtin_inff();
}

// ---------------------------------------------------------------------------
// degree: count incoming edges per dst
// ---------------------------------------------------------------------------
__global__ void degree_kernel(const int* __restrict__ dst, int* __restrict__ deg, int E) {
    int e = blockIdx.x * blockDim.x + threadIdx.x;
    if (e < E) atomicAdd(&deg[dst[e]], 1);
}

// ---------------------------------------------------------------------------
// single-block exclusive scan over deg -> rowptr (and cursor copy)
// ---------------------------------------------------------------------------
__global__ __launch_bounds__(1024)
void scan_kernel(const int* __restrict__ deg, int* __restrict__ rowptr,
                 int* __restrict__ cursor, int n) {
    __shared__ int wsum[16];
    int tid = threadIdx.x;
    int lane = tid & 63;
    int wid = tid >> 6;
    int carry = 0;
    for (int base = 0; base < n; base += 1024) {
        int idx = base + tid;
        int v = (idx < n) ? deg[idx] : 0;
        int x = v;
        #pragma unroll
        for (int off = 1; off < 64; off <<= 1) {
            int t = __shfl_up(x, off, 64);
            if (lane >= off) x += t;
        }
        if (lane == 63) wsum[wid] = x;
        __syncthreads();
        if (wid == 0) {
            int s = (lane < 16) ? wsum[lane] : 0;
            #pragma unroll
            for (int off = 1; off < 16; off <<= 1) {
                int t = __shfl_up(s, off, 64);
                if (lane >= off) s += t;
            }
            if (lane < 16) wsum[lane] = s;
        }
        __syncthreads();
        int woff = (wid == 0) ? 0 : wsum[wid - 1];
        int excl = x + woff - v;
        if (idx < n) { rowptr[idx] = carry + excl; cursor[idx] = carry + excl; }
        carry += wsum[15];
        __syncthreads();
    }
    if (tid == 0) rowptr[n] = carry;
}

// ---------------------------------------------------------------------------
// scatter edges into CSR slots (by dst)
// ---------------------------------------------------------------------------
__global__ void scatter_kernel(const int* __restrict__ src, const int* __restrict__ dst,
                               int* __restrict__ cursor, int* __restrict__ csr, int E) {
    int e = blockIdx.x * blockDim.x + threadIdx.x;
    if (e < E) {
        int slot = atomicAdd(&cursor[dst[e]], 1);
        csr[slot] = src[e];
    }
}

// ---------------------------------------------------------------------------
// fused xl/xr GEMM: xl = X@Wl.T + bl ; xr = X@Wr.T + br   (W: [128][FIN])
// block = 256 threads, 8 rows per block
// ---------------------------------------------------------------------------
template <int FIN>
__global__ __launch_bounds__(256)
void gemm_xlxr_kernel(const float* __restrict__ X,
                      const float* __restrict__ Wl, const float* __restrict__ bl,
                      const float* __restrict__ Wr, const float* __restrict__ br,
                      float* __restrict__ xl, float* __restrict__ xr) {
    __shared__ float Wls[128][33];
    __shared__ float Wrs[128][33];
    __shared__ float Xs[8][33];
    int tid = threadIdx.x;
    int rowBase = blockIdx.x * 8;
    int c = tid & 127;
    int rs = tid >> 7;   // 0 or 1
    float accL[4] = {0.f, 0.f, 0.f, 0.f};
    float accR[4] = {0.f, 0.f, 0.f, 0.f};
    for (int k0 = 0; k0 < FIN; k0 += 32) {
        #pragma unroll
        for (int i = 0; i < 16; ++i) {
            int idx = tid + i * 256;           // 4096 elements
            int cc = idx >> 5, kk = idx & 31;
            Wls[cc][kk] = Wl[cc * FIN + k0 + kk];
            Wrs[cc][kk] = Wr[cc * FIN + k0 + kk];
        }
        {
            int r = tid >> 5, kk = tid & 31;
            Xs[r][kk] = X[(rowBase + r) * FIN + k0 + kk];
        }
        __syncthreads();
        #pragma unroll
        for (int kk = 0; kk < 32; ++kk) {
            float wl = Wls[c][kk], wr = Wrs[c][kk];
            #pragma unroll
            for (int j = 0; j < 4; ++j) {
                float xv = Xs[rs * 4 + j][kk];
                accL[j] = fmaf(xv, wl, accL[j]);
                accR[j] = fmaf(xv, wr, accR[j]);
            }
        }
        __syncthreads();
    }
    float blv = bl[c], brv = br[c];
    #pragma unroll
    for (int j = 0; j < 4; ++j) {
        int row = rowBase + rs * 4 + j;
        xl[row * 128 + c] = accL[j] + blv;
        xr[row * 128 + c] = accR[j] + brv;
    }
}

// ---------------------------------------------------------------------------
// GATv2 node-centric conv: one wave (64 lanes) per node.
// lane covers features f=2*lane, 2*lane+1 (same head h=lane>>4).
// Loop 1: alpha per incoming edge (+self), head-wise shfl reduce, track max.
// Loop 2: exp-sum + weighted accumulation; out = acc/(den*cnt) + cb.
// ---------------------------------------------------------------------------
__global__ __launch_bounds__(256)
void gat_node_kernel(const float* __restrict__ xl, const float* __restrict__ xr,
                     const float* __restrict__ att, const float* __restrict__ cb,
                     const int* __restrict__ rowptr, const int* __restrict__ csr,
                     float* __restrict__ alpha_ws, float* __restrict__ out, int n) {
    int wave = blockIdx.x * (blockDim.x >> 6) + (threadIdx.x >> 6);
    if (wave >= n) return;
    int lane = threadIdx.x & 63;
    int nd = wave;
    int f = lane * 2;
    int hsel = lane >> 4;   // head index 0..3

    float2 xrv = *(const float2*)(xr + nd * 128 + f);
    float2 attv = *(const float2*)(att + f);
    float2 xls = *(const float2*)(xl + nd * 128 + f);   // self-loop source

    int start = rowptr[nd], end = rowptr[nd + 1];

    // self-loop alpha
    float e0 = xls.x + xrv.x; e0 = e0 > 0.f ? e0 : NEG_SLOPE * e0;
    float e1 = xls.y + xrv.y; e1 = e1 > 0.f ? e1 : NEG_SLOPE * e1;
    float p = e0 * attv.x + e1 * attv.y;
    p += __shfl_xor(p, 1); p += __shfl_xor(p, 2);
    p += __shfl_xor(p, 4); p += __shfl_xor(p, 8);
    float aself = p;
    float m = p;

    // pass 1: alphas + max
    for (int i = start; i < end; ++i) {
        int s = csr[i];
        float2 xlv = *(const float2*)(xl + s * 128 + f);
        float a0 = xlv.x + xrv.x; a0 = a0 > 0.f ? a0 : NEG_SLOPE * a0;
        float a1 = xlv.y + xrv.y; a1 = a1 > 0.f ? a1 : NEG_SLOPE * a1;
        float q = a0 * attv.x + a1 * attv.y;
        q += __shfl_xor(q, 1); q += __shfl_xor(q, 2);
        q += __shfl_xor(q, 4); q += __shfl_xor(q, 8);
        m = fmaxf(m, q);
        if ((lane & 15) == 0) alpha_ws[(size_t)i * 4 + hsel] = q;
    }

    // pass 2: exp-sum + accumulate (normalization deferred)
    float den = __expf(aself - m);
    float accx = den * xls.x;
    float accy = den * xls.y;
    for (int i = start; i < end; ++i) {
        int s = csr[i];
        float a = __expf(alpha_ws[(size_t)i * 4 + hsel] - m);
        float2 xlv = *(const float2*)(xl + s * 128 + f);
        den += a;
        accx = fmaf(a, xlv.x, accx);
        accy = fmaf(a, xlv.y, accy);
    }
    float inv = 1.0f / (den * (float)(end - start + 1));
    float2 o;
    o.x = accx * inv + cb[f];
    o.y = accy * inv + cb[f + 1];
    *(float2*)(out + nd * 128 + f) = o;
}

// ---------------------------------------------------------------------------
// linear HD->D: Y[N,32] = X[N,128] @ W.T + b   (W: [32][128])
// ---------------------------------------------------------------------------
__global__ __launch_bounds__(256)
void linear_kernel(const float* __restrict__ X, const float* __restrict__ W,
                   const float* __restrict__ b, float* __restrict__ Y) {
    __shared__ float Ws[32][129];
    __shared__ float Xs[8][129];
    int tid = threadIdx.x;
    int rowBase = blockIdx.x * 8;
    #pragma unroll
    for (int i = 0; i < 16; ++i) {
        int idx = tid + i * 256;               // 4096 = 32*128
        int cc = idx >> 7, k = idx & 127;
        Ws[cc][k] = W[idx];
    }
    #pragma unroll
    for (int i = 0; i < 4; ++i) {
        int idx = tid + i * 256;               // 1024 = 8*128
        int r = idx >> 7, k = idx & 127;
        Xs[r][k] = X[(rowBase + r) * 128 + k];
    }
    __syncthreads();
    int c = tid & 31, r = tid >> 5;
    float acc = 0.f;
    #pragma unroll
    for (int k = 0; k < 128; ++k) acc = fmaf(Xs[r][k], Ws[c][k], acc);
    Y[(rowBase + r) * 32 + c] = acc + b[c];
}

// ---------------------------------------------------------------------------
// global max pool over sorted batch ids (run-length + atomic flush)
// ---------------------------------------------------------------------------
__device__ __forceinline__ void atomicMaxFloat(float* addr, float val) {
    if (val >= 0.f) atomicMax((int*)addr, __float_as_int(val));
    else atomicMin((unsigned int*)addr, (unsigned int)__float_as_int(val));
}

__global__ void pool_kernel(const float* __restrict__ H, const int* __restrict__ batch,
                            float* __restrict__ g, int n) {
    int tid = threadIdx.x;
    int dim = tid & 31;
    int sub = tid >> 5;                 // 0..7
    int nodeStart = blockIdx.x * 128 + sub * 16;
    float m = -__builtin_inff();
    int cur = -1;
    for (int j = 0; j < 16; ++j) {
        int nd = nodeStart + j;
        if (nd >= n) break;
        int b = batch[nd];
        if (b != cur) {
            if (cur >= 0) atomicMaxFloat(&g[cur * 32 + dim], m);
            cur = b; m = -__builtin_inff();
        }
        m = fmaxf(m, H[nd * 32 + dim]);
    }
    if (cur >= 0) atomicMaxFloat(&g[cur * 32 + dim], m);
}

// ---------------------------------------------------------------------------
// final MLP: out = relu(g@fc1.T+b1) @ fc2.T + b2   (single block)
// ---------------------------------------------------------------------------
__global__ __launch_bounds__(256)
void fc_kernel(const float* __restrict__ g,
               const float* __restrict__ fc1W, const float* __restrict__ fc1b,
               const float* __restrict__ fc2W, const float* __restrict__ fc2b,
               float* __restrict__ out) {
    __shared__ float g1[GGRP * DDIM];
    int tid = threadIdx.x;
    for (int idx = tid; idx < GGRP * DDIM; idx += 256) {
        int r = idx >> 5, c = idx & 31;
        float acc = fc1b[c];
        #pragma unroll
        for (int k = 0; k < 32; ++k) acc = fmaf(g[r * 32 + k], fc1W[c * 32 + k], acc);
        g1[idx] = acc > 0.f ? acc : 0.f;
    }
    __syncthreads();
    for (int idx = tid; idx < GGRP * TOUT; idx += 256) {
        int r = idx / TOUT, c = idx - r * TOUT;
        float acc = fc2b[c];
        #pragma unroll
        for (int k = 0; k < 32; ++k) acc = fmaf(g1[r * 32 + k], fc2W[c * 32 + k], acc);
        out[idx] = acc;
    }
}

// ---------------------------------------------------------------------------
extern "C" void kernel_launch(void* const* d_in, const int* in_sizes, int n_in,
                              void* d_out, int out_size, void* d_ws, size_t ws_size,
                              hipStream_t stream) {
    const float* x     = (const float*)d_in[0];
    const int*   ei    = (const int*)d_in[1];     // [2][E]
    const int*   batch = (const int*)d_in[2];
    const float* Wl0 = (const float*)d_in[3];
    const float* bl0 = (const float*)d_in[4];
    const float* Wr0 = (const float*)d_in[5];
    const float* br0 = (const float*)d_in[6];
    const float* at0 = (const float*)d_in[7];
    const float* cb0 = (const float*)d_in[8];
    const float* lw0 = (const float*)d_in[9];
    const float* lb0 = (const float*)d_in[10];
    const float* Wl1 = (const float*)d_in[11];
    const float* bl1 = (const float*)d_in[12];
    const float* Wr1 = (const float*)d_in[13];
    const float* br1 = (const float*)d_in[14];
    const float* at1 = (const float*)d_in[15];
    const float* cb1 = (const float*)d_in[16];
    const float* lw1 = (const float*)d_in[17];
    const float* lb1 = (const float*)d_in[18];
    const float* fc1W = (const float*)d_in[19];
    const float* fc1b = (const float*)d_in[20];
    const float* fc2W = (const float*)d_in[21];
    const float* fc2b = (const float*)d_in[22];

    const int n = in_sizes[0] / 128;      // 30000
    const int E = in_sizes[1] / 2;        // 480000
    const int* src = ei;
    const int* dst = ei + E;

    // workspace layout
    size_t off = 0;
    auto alloc = [&](size_t bytes) {
        void* p = (char*)d_ws + off;
        off += (bytes + 255) & ~(size_t)255;
        return p;
    };
    float* xl    = (float*)alloc((size_t)n * 128 * 4);
    float* xr    = (float*)alloc((size_t)n * 128 * 4);
    float* cout_ = (float*)alloc((size_t)n * 128 * 4);
    float* hbuf  = (float*)alloc((size_t)n * 32 * 4);
    float* alpha = (float*)alloc((size_t)E * 4 * 4);
    int* deg     = (int*)alloc((size_t)n * 4);
    int* rowptr  = (int*)alloc((size_t)(n + 1) * 4);
    int* cursor  = (int*)alloc((size_t)n * 4);
    int* csr     = (int*)alloc((size_t)E * 4);
    float* gpool = (float*)alloc((size_t)GGRP * DDIM * 4);

    // graph structure (shared by both convs)
    init_kernel<<<(n + 255) / 256, 256, 0, stream>>>(deg, gpool, n, GGRP * DDIM);
    degree_kernel<<<(E + 255) / 256, 256, 0, stream>>>(dst, deg, E);
    scan_kernel<<<1, 1024, 0, stream>>>(deg, rowptr, cursor, n);
    scatter_kernel<<<(E + 255) / 256, 256, 0, stream>>>(src, dst, cursor, csr, E);

    // conv 0
    gemm_xlxr_kernel<128><<<n / 8, 256, 0, stream>>>(x, Wl0, bl0, Wr0, br0, xl, xr);
    gat_node_kernel<<<n / 4, 256, 0, stream>>>(xl, xr, at0, cb0, rowptr, csr, alpha, cout_, n);
    linear_kernel<<<n / 8, 256, 0, stream>>>(cout_, lw0, lb0, hbuf);

    // conv 1
    gemm_xlxr_kernel<32><<<n / 8, 256, 0, stream>>>(hbuf, Wl1, bl1, Wr1, br1, xl, xr);
    gat_node_kernel<<<n / 4, 256, 0, stream>>>(xl, xr, at1, cb1, rowptr, csr, alpha, cout_, n);
    linear_kernel<<<n / 8, 256, 0, stream>>>(cout_, lw1, lb1, hbuf);

    // pool + MLP
    pool_kernel<<<(n + 127) / 128, 256, 0, stream>>>(hbuf, batch, gpool, n);
    fc_kernel<<<1, 256, 0, stream>>>(gpool, fc1W, fc1b, fc2W, fc2b, (float*)d_out);
}

// Round 2
// 345.216 us; speedup vs baseline: 1.6208x; 1.6208x over previous
//
#include <hip/hip_runtime.h>
#include <hip/hip_bf16.h>

#define NEG_SLOPE 0.2f
#define GGRP 128
#define TOUT 10

// ---------------------------------------------------------------------------
// init: zero degree array, set pool accumulator to -inf
// ---------------------------------------------------------------------------
__global__ void init_kernel(int* __restrict__ deg, float* __restrict__ gpool,
                            int n, int gsize) {
    int i = blockIdx.x * blockDim.x + threadIdx.x;
    if (i < n) deg[i] = 0;
    if (i < gsize) gpool[i] = -__builtin_inff();
}

// ---------------------------------------------------------------------------
// degree: count incoming edges per dst
// ---------------------------------------------------------------------------
__global__ void degree_kernel(const int* __restrict__ dst, int* __restrict__ deg, int E) {
    int e = blockIdx.x * blockDim.x + threadIdx.x;
    if (e < E) atomicAdd(&deg[dst[e]], 1);
}

// ---------------------------------------------------------------------------
// hierarchical scan: A) per-block exclusive scan + block sums
// ---------------------------------------------------------------------------
__global__ __launch_bounds__(256)
void scanA_kernel(const int* __restrict__ deg, int* __restrict__ rowptr,
                  int* __restrict__ bsum, int n) {
    __shared__ int wsum[4];
    int tid = threadIdx.x, lane = tid & 63, wid = tid >> 6;
    int idx = blockIdx.x * 256 + tid;
    int v = (idx < n) ? deg[idx] : 0;
    int x = v;
    #pragma unroll
    for (int off = 1; off < 64; off <<= 1) {
        int t = __shfl_up(x, off, 64);
        if (lane >= off) x += t;
    }
    if (lane == 63) wsum[wid] = x;
    __syncthreads();
    if (tid == 0) {
        int s = 0;
        #pragma unroll
        for (int i = 0; i < 4; ++i) { int t = wsum[i]; wsum[i] = s; s += t; }
        bsum[blockIdx.x] = s;
    }
    __syncthreads();
    int excl = x - v + wsum[wid];
    if (idx < n) rowptr[idx] = excl;
}

// B) single-wave scan of block sums (nb <= 128)
__global__ void scanB_kernel(const int* __restrict__ bsum, int* __restrict__ boff,
                             int* __restrict__ rowptr, int n, int nb) {
    int lane = threadIdx.x;           // 64 threads
    int v0 = (lane < nb) ? bsum[lane] : 0;
    int v1 = (64 + lane < nb) ? bsum[64 + lane] : 0;
    int s0 = v0, s1 = v1;
    #pragma unroll
    for (int off = 1; off < 64; off <<= 1) {
        int t0 = __shfl_up(s0, off, 64);
        int t1 = __shfl_up(s1, off, 64);
        if (lane >= off) { s0 += t0; s1 += t1; }
    }
    int tot0 = __shfl(s0, 63, 64);
    s1 += tot0;
    boff[lane] = s0 - v0;
    boff[64 + lane] = s1 - v1;
    if (lane == 63) rowptr[n] = s1;   // grand total
}

// C) apply block offsets, fill cursor
__global__ void scanC_kernel(int* __restrict__ rowptr, int* __restrict__ cursor,
                             const int* __restrict__ boff, int n) {
    int idx = blockIdx.x * blockDim.x + threadIdx.x;
    if (idx < n) {
        int r = rowptr[idx] + boff[idx >> 8];
        rowptr[idx] = r;
        cursor[idx] = r;
    }
}

// ---------------------------------------------------------------------------
// scatter edges into CSR slots (by dst)
// ---------------------------------------------------------------------------
__global__ void scatter_kernel(const int* __restrict__ src, const int* __restrict__ dst,
                               int* __restrict__ cursor, int* __restrict__ csr, int E) {
    int e = blockIdx.x * blockDim.x + threadIdx.x;
    if (e < E) {
        int slot = atomicAdd(&cursor[dst[e]], 1);
        csr[slot] = src[e];
    }
}

// ---------------------------------------------------------------------------
// fused xl/xr GEMM: xl = X@Wl.T + bl ; xr = X@Wr.T + br   (W: [128][FIN])
// 256 threads, 16 rows/block, float4 LDS reads (pad 36 -> stride 4 mod 32)
// ---------------------------------------------------------------------------
template <int FIN>
__global__ __launch_bounds__(256)
void gemm_xlxr_kernel(const float* __restrict__ X,
                      const float* __restrict__ Wl, const float* __restrict__ bl,
                      const float* __restrict__ Wr, const float* __restrict__ br,
                      float* __restrict__ xl, float* __restrict__ xr) {
    __shared__ float Wls[128][36];
    __shared__ float Wrs[128][36];
    __shared__ float Xs[16][36];
    int tid = threadIdx.x;
    int rowBase = blockIdx.x * 16;
    int c = tid & 127;
    int rs = tid >> 7;   // 0 or 1 -> rows rs*8 .. rs*8+7
    float accL[8] = {0.f}, accR[8] = {0.f};
    for (int k0 = 0; k0 < FIN; k0 += 32) {
        #pragma unroll
        for (int i = 0; i < 16; ++i) {
            int idx = tid + i * 256;           // 4096 = 128*32
            int cc = idx >> 5, kk = idx & 31;
            Wls[cc][kk] = Wl[cc * FIN + k0 + kk];
            Wrs[cc][kk] = Wr[cc * FIN + k0 + kk];
        }
        #pragma unroll
        for (int i = 0; i < 2; ++i) {
            int idx = tid + i * 256;           // 512 = 16*32
            int r = idx >> 5, kk = idx & 31;
            Xs[r][kk] = X[(rowBase + r) * FIN + k0 + kk];
        }
        __syncthreads();
        #pragma unroll
        for (int k4 = 0; k4 < 32; k4 += 4) {
            float4 wl4 = *(const float4*)&Wls[c][k4];
            float4 wr4 = *(const float4*)&Wrs[c][k4];
            #pragma unroll
            for (int j = 0; j < 8; ++j) {
                float4 xv = *(const float4*)&Xs[rs * 8 + j][k4];
                accL[j] = fmaf(xv.x, wl4.x, accL[j]);
                accL[j] = fmaf(xv.y, wl4.y, accL[j]);
                accL[j] = fmaf(xv.z, wl4.z, accL[j]);
                accL[j] = fmaf(xv.w, wl4.w, accL[j]);
                accR[j] = fmaf(xv.x, wr4.x, accR[j]);
                accR[j] = fmaf(xv.y, wr4.y, accR[j]);
                accR[j] = fmaf(xv.z, wr4.z, accR[j]);
                accR[j] = fmaf(xv.w, wr4.w, accR[j]);
            }
        }
        __syncthreads();
    }
    float blv = bl[c], brv = br[c];
    #pragma unroll
    for (int j = 0; j < 8; ++j) {
        int row = rowBase + rs * 8 + j;
        xl[row * 128 + c] = accL[j] + blv;
        xr[row * 128 + c] = accR[j] + brv;
    }
}

// ---------------------------------------------------------------------------
// Fused GATv2 conv + Linear(HD->D).
// One wave per node; 2 edges in flight (32 lanes / edge, float4 per lane).
// Single-pass softmax (no max subtraction: |alpha| ~ 0.2, exp is safe).
// Epilogue: conv-out vector -> LDS slot -> y = out @ lw.T + lb  (fused).
// ---------------------------------------------------------------------------
__global__ __launch_bounds__(256)
void gat_fused_kernel(const float* __restrict__ xl, const float* __restrict__ xr,
                      const float* __restrict__ att, const float* __restrict__ cb,
                      const float* __restrict__ lw, const float* __restrict__ lb,
                      const int* __restrict__ rowptr, const int* __restrict__ csr,
                      float* __restrict__ out /*[n][32]*/, int n) {
    __shared__ float lws[32][132];     // lw staged, pad 132 (stride 4 mod 32)
    __shared__ float oslot[4][128];    // per-wave conv-out vector
    int tid = threadIdx.x;
    #pragma unroll
    for (int i = 0; i < 16; ++i) {
        int idx = tid + i * 256;       // 4096 = 32*128
        lws[idx >> 7][idx & 127] = lw[idx];
    }
    __syncthreads();

    int wid = tid >> 6, lane = tid & 63;
    int nd = blockIdx.x * 4 + wid;
    if (nd >= n) return;
    int half = lane >> 5;              // which edge of the pair
    int l32 = lane & 31;
    int f4 = l32 * 4;                  // features f4..f4+3 (head = l32>>3)

    const float4 xr4  = *(const float4*)(xr + nd * 128 + f4);
    const float4 at4  = *(const float4*)(att + f4);
    const float4 xls4 = *(const float4*)(xl + nd * 128 + f4);

    int start = rowptr[nd], end = rowptr[nd + 1];

    // self-loop (counted once, on half 0)
    float den;
    float4 acc;
    {
        float e0 = xls4.x + xr4.x; e0 = e0 > 0.f ? e0 : NEG_SLOPE * e0;
        float e1 = xls4.y + xr4.y; e1 = e1 > 0.f ? e1 : NEG_SLOPE * e1;
        float e2 = xls4.z + xr4.z; e2 = e2 > 0.f ? e2 : NEG_SLOPE * e2;
        float e3 = xls4.w + xr4.w; e3 = e3 > 0.f ? e3 : NEG_SLOPE * e3;
        float q = e0 * at4.x + e1 * at4.y + e2 * at4.z + e3 * at4.w;
        q += __shfl_xor(q, 1); q += __shfl_xor(q, 2); q += __shfl_xor(q, 4);
        float a = __expf(q);
        if (half == 0) {
            den = a;
            acc.x = a * xls4.x; acc.y = a * xls4.y;
            acc.z = a * xls4.z; acc.w = a * xls4.w;
        } else {
            den = 0.f; acc.x = acc.y = acc.z = acc.w = 0.f;
        }
    }

    // edges: half h takes i = start+h, start+h+2, ...
    for (int i = start + half; i < end; i += 2) {
        int s = csr[i];
        float4 xv = *(const float4*)(xl + (size_t)s * 128 + f4);
        float e0 = xv.x + xr4.x; e0 = e0 > 0.f ? e0 : NEG_SLOPE * e0;
        float e1 = xv.y + xr4.y; e1 = e1 > 0.f ? e1 : NEG_SLOPE * e1;
        float e2 = xv.z + xr4.z; e2 = e2 > 0.f ? e2 : NEG_SLOPE * e2;
        float e3 = xv.w + xr4.w; e3 = e3 > 0.f ? e3 : NEG_SLOPE * e3;
        float q = e0 * at4.x + e1 * at4.y + e2 * at4.z + e3 * at4.w;
        q += __shfl_xor(q, 1); q += __shfl_xor(q, 2); q += __shfl_xor(q, 4);
        float a = __expf(q);
        den += a;
        acc.x = fmaf(a, xv.x, acc.x);
        acc.y = fmaf(a, xv.y, acc.y);
        acc.z = fmaf(a, xv.z, acc.z);
        acc.w = fmaf(a, xv.w, acc.w);
    }

    // combine the two halves
    acc.x += __shfl_xor(acc.x, 32);
    acc.y += __shfl_xor(acc.y, 32);
    acc.z += __shfl_xor(acc.z, 32);
    acc.w += __shfl_xor(acc.w, 32);
    den   += __shfl_xor(den, 32);

    float inv = 1.0f / (den * (float)(end - start + 1));
    const float4 cb4 = *(const float4*)(cb + f4);
    float4 o;
    o.x = fmaf(acc.x, inv, cb4.x);
    o.y = fmaf(acc.y, inv, cb4.y);
    o.z = fmaf(acc.z, inv, cb4.z);
    o.w = fmaf(acc.w, inv, cb4.w);

    if (half == 0) *(float4*)&oslot[wid][f4] = o;
    asm volatile("s_waitcnt lgkmcnt(0)" ::: "memory");

    // fused linear: y[c] = sum_k o[k]*lw[c][k]; c=l32, k-range split by half
    float y = 0.f;
    int kbase = half * 64;
    #pragma unroll
    for (int k = 0; k < 64; k += 4) {
        float4 lv = *(const float4*)&lws[l32][kbase + k];
        float4 ov = *(const float4*)&oslot[wid][kbase + k];
        y = fmaf(lv.x, ov.x, y);
        y = fmaf(lv.y, ov.y, y);
        y = fmaf(lv.z, ov.z, y);
        y = fmaf(lv.w, ov.w, y);
    }
    y += __shfl_xor(y, 32);
    if (half == 0) out[nd * 32 + l32] = y + lb[l32];
}

// ---------------------------------------------------------------------------
// global max pool over sorted batch ids (run-length + atomic flush)
// ---------------------------------------------------------------------------
__device__ __forceinline__ void atomicMaxFloat(float* addr, float val) {
    if (val >= 0.f) atomicMax((int*)addr, __float_as_int(val));
    else atomicMin((unsigned int*)addr, (unsigned int)__float_as_int(val));
}

__global__ void pool_kernel(const float* __restrict__ H, const int* __restrict__ batch,
                            float* __restrict__ g, int n) {
    int tid = threadIdx.x;
    int dim = tid & 31;
    int sub = tid >> 5;                 // 0..7
    int nodeStart = blockIdx.x * 128 + sub * 16;
    float m = -__builtin_inff();
    int cur = -1;
    for (int j = 0; j < 16; ++j) {
        int nd = nodeStart + j;
        if (nd >= n) break;
        int b = batch[nd];
        if (b != cur) {
            if (cur >= 0) atomicMaxFloat(&g[cur * 32 + dim], m);
            cur = b; m = -__builtin_inff();
        }
        m = fmaxf(m, H[nd * 32 + dim]);
    }
    if (cur >= 0) atomicMaxFloat(&g[cur * 32 + dim], m);
}

// ---------------------------------------------------------------------------
// final MLP: out = relu(g@fc1.T+b1) @ fc2.T + b2   (single block)
// ---------------------------------------------------------------------------
__global__ __launch_bounds__(256)
void fc_kernel(const float* __restrict__ g,
               const float* __restrict__ fc1W, const float* __restrict__ fc1b,
               const float* __restrict__ fc2W, const float* __restrict__ fc2b,
               float* __restrict__ out) {
    __shared__ float g1[GGRP * 32];
    int tid = threadIdx.x;
    for (int idx = tid; idx < GGRP * 32; idx += 256) {
        int r = idx >> 5, c = idx & 31;
        float acc = fc1b[c];
        #pragma unroll
        for (int k = 0; k < 32; ++k) acc = fmaf(g[r * 32 + k], fc1W[c * 32 + k], acc);
        g1[idx] = acc > 0.f ? acc : 0.f;
    }
    __syncthreads();
    for (int idx = tid; idx < GGRP * TOUT; idx += 256) {
        int r = idx / TOUT, c = idx - r * TOUT;
        float acc = fc2b[c];
        #pragma unroll
        for (int k = 0; k < 32; ++k) acc = fmaf(g1[r * 32 + k], fc2W[c * 32 + k], acc);
        out[idx] = acc;
    }
}

// ---------------------------------------------------------------------------
extern "C" void kernel_launch(void* const* d_in, const int* in_sizes, int n_in,
                              void* d_out, int out_size, void* d_ws, size_t ws_size,
                              hipStream_t stream) {
    const float* x     = (const float*)d_in[0];
    const int*   ei    = (const int*)d_in[1];     // [2][E]
    const int*   batch = (const int*)d_in[2];
    const float* Wl0 = (const float*)d_in[3];
    const float* bl0 = (const float*)d_in[4];
    const float* Wr0 = (const float*)d_in[5];
    const float* br0 = (const float*)d_in[6];
    const float* at0 = (const float*)d_in[7];
    const float* cb0 = (const float*)d_in[8];
    const float* lw0 = (const float*)d_in[9];
    const float* lb0 = (const float*)d_in[10];
    const float* Wl1 = (const float*)d_in[11];
    const float* bl1 = (const float*)d_in[12];
    const float* Wr1 = (const float*)d_in[13];
    const float* br1 = (const float*)d_in[14];
    const float* at1 = (const float*)d_in[15];
    const float* cb1 = (const float*)d_in[16];
    const float* lw1 = (const float*)d_in[17];
    const float* lb1 = (const float*)d_in[18];
    const float* fc1W = (const float*)d_in[19];
    const float* fc1b = (const float*)d_in[20];
    const float* fc2W = (const float*)d_in[21];
    const float* fc2b = (const float*)d_in[22];

    const int n = in_sizes[0] / 128;      // 30000
    const int E = in_sizes[1] / 2;        // 480000
    const int* src = ei;
    const int* dst = ei + E;
    const int nblkScan = (n + 255) / 256; // 118

    // workspace layout
    size_t off = 0;
    auto alloc = [&](size_t bytes) {
        void* p = (char*)d_ws + off;
        off += (bytes + 255) & ~(size_t)255;
        return p;
    };
    float* xl    = (float*)alloc((size_t)n * 128 * 4);
    float* xr    = (float*)alloc((size_t)n * 128 * 4);
    float* hbuf  = (float*)alloc((size_t)n * 32 * 4);
    int* deg     = (int*)alloc((size_t)n * 4);
    int* rowptr  = (int*)alloc((size_t)(n + 1) * 4);
    int* cursor  = (int*)alloc((size_t)n * 4);
    int* csr     = (int*)alloc((size_t)E * 4);
    int* bsum    = (int*)alloc(128 * 4);
    int* boff    = (int*)alloc(128 * 4);
    float* gpool = (float*)alloc((size_t)GGRP * 32 * 4);

    // graph structure (shared by both convs)
    init_kernel<<<(n + 255) / 256, 256, 0, stream>>>(deg, gpool, n, GGRP * 32);
    degree_kernel<<<(E + 255) / 256, 256, 0, stream>>>(dst, deg, E);
    scanA_kernel<<<nblkScan, 256, 0, stream>>>(deg, rowptr, bsum, n);
    scanB_kernel<<<1, 64, 0, stream>>>(bsum, boff, rowptr, n, nblkScan);
    scanC_kernel<<<nblkScan, 256, 0, stream>>>(rowptr, cursor, boff, n);
    scatter_kernel<<<(E + 255) / 256, 256, 0, stream>>>(src, dst, cursor, csr, E);

    // conv 0 (fused conv+linear)
    gemm_xlxr_kernel<128><<<n / 16, 256, 0, stream>>>(x, Wl0, bl0, Wr0, br0, xl, xr);
    gat_fused_kernel<<<(n + 3) / 4, 256, 0, stream>>>(xl, xr, at0, cb0, lw0, lb0,
                                                      rowptr, csr, hbuf, n);
    // conv 1
    gemm_xlxr_kernel<32><<<n / 16, 256, 0, stream>>>(hbuf, Wl1, bl1, Wr1, br1, xl, xr);
    gat_fused_kernel<<<(n + 3) / 4, 256, 0, stream>>>(xl, xr, at1, cb1, lw1, lb1,
                                                      rowptr, csr, hbuf, n);

    // pool + MLP
    pool_kernel<<<(n + 127) / 128, 256, 0, stream>>>(hbuf, batch, gpool, n);
    fc_kernel<<<1, 256, 0, stream>>>(gpool, fc1W, fc1b, fc2W, fc2b, (float*)d_out);
}